// Round 4
// baseline (3539.827 us; speedup 1.0000x reference)
//
#include <hip/hip_runtime.h>

typedef unsigned short u16;
typedef unsigned int u32;
typedef float f32x4 __attribute__((ext_vector_type(4)));
typedef __bf16 bf16x8 __attribute__((ext_vector_type(8)));
typedef u16 u16x8 __attribute__((ext_vector_type(8)));

__device__ __forceinline__ float bf2f(u16 v) {
  union { u32 u; float f; } c; c.u = ((u32)v) << 16; return c.f;
}
__device__ __forceinline__ u16 f2bf(float f) {
  union { float f; u32 u; } c; c.f = f;
  c.u += 0x7fffu + ((c.u >> 16) & 1u);
  return (u16)(c.u >> 16);
}
__device__ __forceinline__ float fast_tanh(float x) {
  float e = __expf(2.0f * x);
  return 1.0f - 2.0f / (e + 1.0f);   // NaN-safe at +/-inf of e
}
__device__ __forceinline__ void gload16(const void* g, void* l) {
  __builtin_amdgcn_global_load_lds((const __attribute__((address_space(1))) void*)g,
                                   (__attribute__((address_space(3))) void*)l, 16, 0, 0);
}
__device__ __forceinline__ bf16x8 ldfrag(const u16* p) {
  return __builtin_bit_cast(bf16x8, *(const u16x8*)p);
}

// ---------------------------------------------------------------- prep kernels
__global__ __launch_bounds__(256) void conv_bf(const float* __restrict__ s,
                                               u16* __restrict__ d, long n) {
  const long i = (long)blockIdx.x * 256 + threadIdx.x;
  if (i < n) d[i] = f2bf(s[i]);
}

// dst[l][n][k] = bf16(src[l][k][n])   (weights stored transposed, N x K row-major)
__global__ __launch_bounds__(256) void trans_conv(const float* __restrict__ src,
                                                  u16* __restrict__ dst,
                                                  int K, int N, int batch) {
  const long total = (long)batch * K * N;
  const long idx = (long)blockIdx.x * 256 + threadIdx.x;
  if (idx >= total) return;
  const long l = idx / ((long)K * N);
  const long rem = idx - l * (long)K * N;
  const int n = (int)(rem / K);
  const int k = (int)(rem - (long)n * K);
  dst[idx] = f2bf(src[l * (long)K * N + (long)k * N + n]);
}

// Quaternion block-matrix, stored transposed: dst[n*512+k] = sign[kb][nb]*Wsel[kc][nc]
__global__ __launch_bounds__(256) void build_quat(const float* __restrict__ wr,
                                                  const float* __restrict__ wi,
                                                  const float* __restrict__ wj,
                                                  const float* __restrict__ wk,
                                                  u16* __restrict__ dst) {
  const int idx = blockIdx.x * 256 + threadIdx.x;   // n*512+k, 262144 total
  const int n = idx >> 9, k = idx & 511;
  const int kb = k >> 7, kc = k & 127, nb = n >> 7, nc = n & 127;
  const float* const srcs[4] = {wr, wi, wj, wk};
  const float sgn[4][4] = {{1,1,1,1},{-1,1,-1,1},{-1,1,1,-1},{-1,-1,1,1}};
  dst[idx] = f2bf(sgn[kb][nb] * srcs[kb ^ nb][kc * 128 + nc]);
}

// Wavelet fold, stored transposed: equal parity -> (lo+hi)/2, diff -> (lo-hi)/2
__global__ __launch_bounds__(256) void build_wav(const float* __restrict__ lo,
                                                 const float* __restrict__ hi,
                                                 u16* __restrict__ dst) {
  const int idx = blockIdx.x * 256 + threadIdx.x;   // n*512+k
  const int n = idx >> 9, k = idx & 511;
  const int d = k >> 1, c = n >> 1;
  const float a = lo[d * 256 + c], b = hi[d * 256 + c];
  dst[idx] = f2bf(((k ^ n) & 1) ? 0.5f * (a - b) : 0.5f * (a + b));
}

// ---------------------------------------------------------------- GEMM core
// 128x128 tile, BK=64, 4 waves each 64x64 (4x4 16x16x32 bf16 MFMA frags),
// global_load_lds(16) staging (m97 structure). B is pre-transposed (N x K).
// EPI: 0=none->bf16  1=bias+leaky->bf16  2=bias+tanh->bf16  3=bias->f32  4=none->f32
template<int EPI, int NT>
__global__ __launch_bounds__(256, 2)
void gemm_k(const u16* __restrict__ A, int arow,
            const u16* __restrict__ BT0, const u16* __restrict__ BT1,
            const u16* __restrict__ BT2,
            u16* __restrict__ C0, u16* __restrict__ C1, u16* __restrict__ C2,
            float* __restrict__ Cf, const float* __restrict__ bias,
            int M, int N, int K) {
  __shared__ u16 lsA[128 * 64];
  __shared__ u16 lsB[128 * 64];
  const int tid = threadIdx.x;
  const int mblk = M >> 7;
  const int bm = (int)blockIdx.x % mblk;
  const int bn = (int)blockIdx.x / mblk;
  const long m0 = (long)bm << 7;
  const int n0 = bn << 7;
  const int w = tid >> 6, lane = tid & 63;
  const int wrow = ((w >> 1) & 1) << 6;
  const int wcol = (w & 1) << 6;
  const int lr = lane & 15, lg = lane >> 4;

  const u16* const BTs[3] = {BT0, BT1, BT2};
  u16* const Cs[3] = {C0, C1, C2};

  #pragma unroll 1
  for (int t = 0; t < NT; ++t) {
    const u16* const BT = BTs[t];
    f32x4 acc[4][4];
    #pragma unroll
    for (int i = 0; i < 4; ++i)
      #pragma unroll
      for (int j = 0; j < 4; ++j)
        acc[i][j] = (f32x4){0.f, 0.f, 0.f, 0.f};

    for (int kt = 0; kt < K; kt += 64) {
      __syncthreads();                          // protect LDS from prior reads
      #pragma unroll
      for (int r = 0; r < 4; ++r) {             // A tile: 1024 16B chunks
        const int chunk = r * 256 + tid;
        const int row = chunk >> 3, cc = (chunk & 7) << 3;
        gload16(A + (m0 + row) * (long)arow + kt + cc, &lsA[chunk * 8]);
      }
      #pragma unroll
      for (int r = 0; r < 4; ++r) {             // B^T tile
        const int chunk = r * 256 + tid;
        const int row = chunk >> 3, cc = (chunk & 7) << 3;
        gload16(BT + (size_t)(n0 + row) * K + kt + cc, &lsB[chunk * 8]);
      }
      __syncthreads();                          // vmcnt(0) drain before barrier
      #pragma unroll
      for (int kk = 0; kk < 64; kk += 32) {
        bf16x8 af[4], bfr[4];
        #pragma unroll
        for (int m = 0; m < 4; ++m)
          af[m] = ldfrag(&lsA[(wrow + m * 16 + lr) * 64 + kk + lg * 8]);
        #pragma unroll
        for (int n = 0; n < 4; ++n)
          bfr[n] = ldfrag(&lsB[(wcol + n * 16 + lr) * 64 + kk + lg * 8]);
        #pragma unroll
        for (int m = 0; m < 4; ++m)
          #pragma unroll
          for (int n = 0; n < 4; ++n)
            acc[m][n] = __builtin_amdgcn_mfma_f32_16x16x32_bf16(
                af[m], bfr[n], acc[m][n], 0, 0, 0);
      }
    }
    // epilogue: C/D layout col=lane&15, row=(lane>>4)*4+reg (m89-verified)
    u16* const C = Cs[t];
    #pragma unroll
    for (int m = 0; m < 4; ++m) {
      const long rbase = m0 + wrow + m * 16 + lg * 4;
      #pragma unroll
      for (int n = 0; n < 4; ++n) {
        const int col = n0 + wcol + n * 16 + lr;
        float bv = 0.f;
        if (EPI == 1 || EPI == 2 || EPI == 3) bv = bias[col];
        #pragma unroll
        for (int j = 0; j < 4; ++j) {
          float v = acc[m][n][j];
          const long row = rbase + j;
          if (EPI == 1) { v += bv; v = v > 0.f ? v : 0.01f * v; }
          if (EPI == 2) { v += bv; v = fast_tanh(v); }
          if (EPI == 3) { v += bv; }
          if (EPI == 3 || EPI == 4) Cf[row * N + col] = v;
          else                      C[row * N + col] = f2bf(v);
        }
      }
    }
  }
}

// ---------------------------------------------------------------- vortex agg
// m[b,node,:] = 0.5*(z[b,node,:] + z[b,(5*node+4)%9,:])   (node 8 -> itself)
__global__ __launch_bounds__(256) void agg_k(const u16* __restrict__ z,
                                             u16* __restrict__ mo) {
  const long idx = (long)blockIdx.x * 256 + threadIdx.x;  // u16x8 chunk id
  const int h0 = (int)(idx & 63) << 3;
  const long row = idx >> 6;
  const long b = row / 9;
  const int node = (int)(row - b * 9);
  const int srcn = (5 * node + 4) % 9;
  const u16x8 a = *(const u16x8*)&z[row * 512 + h0];
  const u16x8 c = *(const u16x8*)&z[(b * 9 + srcn) * 512 + h0];
  u16x8 o;
  #pragma unroll
  for (int u = 0; u < 8; ++u) o[u] = f2bf(0.5f * (bf2f(a[u]) + bf2f(c[u])));
  *(u16x8*)&mo[row * 512 + h0] = o;
}

// ---------------------------------------------------------------- attention core
// one wave per batch: stage q,k,v (9x512 each) to LDS, scores via 16 MFMAs,
// wave-parallel softmax over 9 keys, PV on VALU.
__global__ __launch_bounds__(64)
void attn_k(const u16* __restrict__ q, const u16* __restrict__ k,
            const u16* __restrict__ v, u16* __restrict__ out) {
  __shared__ u16 ls[27 * 512];
  __shared__ float laf[256];
  const long b = blockIdx.x;
  const int lane = threadIdx.x;
  {
    const u16* const srcs[3] = {q, k, v};
    #pragma unroll
    for (int t = 0; t < 3; ++t)
      #pragma unroll
      for (int c = 0; c < 9; ++c)
        gload16(srcs[t] + (b * 9 + c) * 512 + lane * 8,
                &ls[(t * 9 + c) * 512 + lane * 8]);
  }
  __syncthreads();
  const int lr = lane & 15, lg = lane >> 4;
  const int rr = lr > 8 ? 8 : lr;               // clamp pad rows (finite data)
  f32x4 sacc = {0.f, 0.f, 0.f, 0.f};
  #pragma unroll
  for (int kc = 0; kc < 16; ++kc) {
    const bf16x8 qa = ldfrag(&ls[rr * 512 + kc * 32 + lg * 8]);
    const bf16x8 kb = ldfrag(&ls[(9 + rr) * 512 + kc * 32 + lg * 8]);
    sacc = __builtin_amdgcn_mfma_f32_16x16x32_bf16(qa, kb, sacc, 0, 0, 0);
  }
  const float scale = 0.0441941738241592f;      // 1/sqrt(512)
  #pragma unroll
  for (int r = 0; r < 4; ++r) {
    float s = sacc[r] * scale;
    if (lr > 8) s = -1e30f;                     // invalid key col
    float mx = s;
    #pragma unroll
    for (int m = 1; m < 16; m <<= 1) mx = fmaxf(mx, __shfl_xor(mx, m, 16));
    const float e = __expf(s - mx);             // -> 0 for lr>8
    float sum = e;
    #pragma unroll
    for (int m = 1; m < 16; m <<= 1) sum += __shfl_xor(sum, m, 16);
    laf[(lg * 4 + r) * 16 + lr] = e / sum;      // a[i][j], i=lg*4+r, j=lr
  }
  __syncthreads();
  const u16* const lsv = &ls[18 * 512];
  #pragma unroll 1
  for (int i = 0; i < 9; ++i) {
    float o[8] = {0, 0, 0, 0, 0, 0, 0, 0};
    #pragma unroll
    for (int j = 0; j < 9; ++j) {
      const float aij = laf[i * 16 + j];        // LDS broadcast
      const u16x8 v8 = *(const u16x8*)&lsv[j * 512 + lane * 8];
      #pragma unroll
      for (int u = 0; u < 8; ++u) o[u] += aij * bf2f(v8[u]);
    }
    u16x8 ov;
    #pragma unroll
    for (int u = 0; u < 8; ++u) ov[u] = f2bf(o[u]);
    *(u16x8*)&out[(b * 9 + i) * 512 + lane * 8] = ov;
  }
}

// ---------------------------------------------------------------- drnorm+residual
// out = z + gamma*(y-mu)*rsqrt(var+1e-5) + beta, per 512-row; y is f32.
__global__ __launch_bounds__(256)
void norm_k(const float* __restrict__ y, const u16* __restrict__ z,
            const float* __restrict__ gamma, const float* __restrict__ beta,
            u16* __restrict__ out) {
  const int w = threadIdx.x >> 6, lane = threadIdx.x & 63;
  const long row = (long)blockIdx.x * 4 + w;
  const long base = row * 512 + lane * 8;
  const f32x4 ylo = *(const f32x4*)&y[base];
  const f32x4 yhi = *(const f32x4*)&y[base + 4];
  float f[8] = {ylo[0], ylo[1], ylo[2], ylo[3], yhi[0], yhi[1], yhi[2], yhi[3]};
  float s1 = 0.f, s2 = 0.f;
  #pragma unroll
  for (int u = 0; u < 8; ++u) { s1 += f[u]; s2 += f[u] * f[u]; }
  #pragma unroll
  for (int m = 1; m < 64; m <<= 1) {
    s1 += __shfl_xor(s1, m, 64); s2 += __shfl_xor(s2, m, 64);
  }
  const float mu = s1 * (1.f / 512.f);
  const float rv = rsqrtf(s2 * (1.f / 512.f) - mu * mu + 1e-5f);
  const u16x8 z8 = *(const u16x8*)&z[base];
  u16x8 o;
  #pragma unroll
  for (int u = 0; u < 8; ++u) {
    const int col = lane * 8 + u;
    o[u] = f2bf(bf2f(z8[u]) + gamma[col] * (f[u] - mu) * rv + beta[col]);
  }
  *(u16x8*)&out[base] = o;
}

// ---------------------------------------------------------------- launcher
extern "C" void kernel_launch(void* const* d_in, const int* in_sizes, int n_in,
                              void* d_out, int out_size, void* d_ws, size_t ws_size,
                              hipStream_t stream) {
  (void)in_sizes; (void)n_in; (void)out_size;
  const float* x      = (const float*)d_in[0];
  const float* W_in   = (const float*)d_in[1];
  const float* b_in   = (const float*)d_in[2];
  const float* W_dr   = (const float*)d_in[3];
  const float* b_dr   = (const float*)d_in[4];
  const float* W_hyp  = (const float*)d_in[5];
  const float* b_hyp  = (const float*)d_in[6];
  const float* Wq_r   = (const float*)d_in[7];
  const float* Wq_i   = (const float*)d_in[8];
  const float* Wq_j   = (const float*)d_in[9];
  const float* Wq_k   = (const float*)d_in[10];
  const float* b_quat = (const float*)d_in[11];
  const float* W_low  = (const float*)d_in[12];
  const float* W_high = (const float*)d_in[13];
  const float* b_wav  = (const float*)d_in[14];
  const float* aWq    = (const float*)d_in[15];
  const float* aWk    = (const float*)d_in[16];
  const float* aWv    = (const float*)d_in[17];
  const float* aWo    = (const float*)d_in[18];
  const float* gamma  = (const float*)d_in[19];
  const float* beta   = (const float*)d_in[20];
  const float* W_out  = (const float*)d_in[21];
  const float* b_out  = (const float*)d_in[22];
  float* out = (float*)d_out;

  // ---- workspace layout: [weights 13.2 MB][per-chunk activations] ----
  char* ws = (char*)d_ws;
  char* wp = ws;
  u16* WinT = (u16*)wp; wp += (size_t)4608 * 512 * 2;   // 4,718,592
  u16* WdrT = (u16*)wp; wp += 524288;
  u16* WhyT = (u16*)wp; wp += 524288;
  u16* WquT = (u16*)wp; wp += 524288;
  u16* WwvT = (u16*)wp; wp += 524288;
  u16* WqT  = (u16*)wp; wp += 3 * 524288;
  u16* WkT  = (u16*)wp; wp += 3 * 524288;
  u16* WvT  = (u16*)wp; wp += 3 * 524288;
  u16* WoT  = (u16*)wp; wp += 3 * 524288;
  u16* WouT = (u16*)wp; wp += 131072;
  const size_t woff = (size_t)(wp - ws);                // 13,238,272

  // chunk count: smallest NC (>=2, power of 2) whose footprint fits ws_size.
  // per-chunk bytes = CB*1024 (xbf) + 4*CB*9216 (bf16 act buffers) = CB*37888.
  int nc = 2;
  while (nc < 64 &&
         woff + (size_t)(16384 / nc) * 37888ULL > ws_size) nc *= 2;
  const int CB = 16384 / nc;                            // batch rows per chunk
  const int CR = CB * 9;                                // activation rows

  char* cbase = ws + woff;
  u16* xbf  = (u16*)cbase;                              // CB x 512 bf16
  u16* buf0 = (u16*)(cbase + (size_t)CB * 1024);
  u16* buf1 = buf0 + (size_t)CB * 4608;
  u16* buf2 = buf1 + (size_t)CB * 4608;
  u16* buf3 = buf2 + (size_t)CB * 4608;
  float* yf = (float*)buf2;                             // f32 y over buf2+buf3

  // ---- weight prep (once per launch) ----
  trans_conv<<<9216, 256, 0, stream>>>(W_in, WinT, 512, 4608, 1);
  trans_conv<<<1024, 256, 0, stream>>>(W_dr, WdrT, 512, 512, 1);
  trans_conv<<<1024, 256, 0, stream>>>(W_hyp, WhyT, 512, 512, 1);
  trans_conv<<<3072, 256, 0, stream>>>(aWq, WqT, 512, 512, 3);
  trans_conv<<<3072, 256, 0, stream>>>(aWk, WkT, 512, 512, 3);
  trans_conv<<<3072, 256, 0, stream>>>(aWv, WvT, 512, 512, 3);
  trans_conv<<<3072, 256, 0, stream>>>(aWo, WoT, 512, 512, 3);
  trans_conv<<<256, 256, 0, stream>>>(W_out, WouT, 512, 128, 1);
  build_quat<<<1024, 256, 0, stream>>>(Wq_r, Wq_i, Wq_j, Wq_k, WquT);
  build_wav<<<1024, 256, 0, stream>>>(W_low, W_high, WwvT);

  const int gemmN512 = (CR >> 7) * 4;                   // grid for (CR,512) gemm
  const int rowsDiv4 = CR >> 2;                         // grid for agg/norm

  for (int c = 0; c < nc; ++c) {
    const size_t b0 = (size_t)c * CB;
    // x chunk -> bf16
    conv_bf<<<CB * 2, 256, 0, stream>>>(x + b0 * 512, xbf, (long)CB * 512);
    // p = leaky(x@W_in+b_in)        (M=CB, N=4608)
    gemm_k<1, 1><<<(CB >> 7) * 36, 256, 0, stream>>>(
        xbf, 512, WinT, WinT, WinT, buf0, buf0, buf0, nullptr, b_in,
        CB, 4608, 512);
    // nf = tanh(p@W_dr+b_dr)
    gemm_k<2, 1><<<gemmN512, 256, 0, stream>>>(
        buf0, 512, WdrT, WdrT, WdrT, buf1, buf1, buf1, nullptr, b_dr,
        CR, 512, 512);
    agg_k<<<rowsDiv4, 256, 0, stream>>>(buf1, buf2);
    // z = tanh(agg@W_hyp+b_hyp)
    gemm_k<2, 1><<<gemmN512, 256, 0, stream>>>(
        buf2, 512, WhyT, WhyT, WhyT, buf0, buf0, buf0, nullptr, b_hyp,
        CR, 512, 512);

    for (int l = 0; l < 3; ++l) {
      const u16* wq = WqT + (size_t)l * 262144;
      const u16* wk = WkT + (size_t)l * 262144;
      const u16* wv = WvT + (size_t)l * 262144;
      const u16* wo = WoT + (size_t)l * 262144;
      // q,k,v (A-tile reused from L2 across the 3 weights)
      gemm_k<0, 3><<<gemmN512, 256, 0, stream>>>(
          buf0, 512, wq, wk, wv, buf1, buf2, buf3, nullptr, nullptr,
          CR, 512, 512);
      attn_k<<<CB, 64, 0, stream>>>(buf1, buf2, buf3, buf1);
      // y = attn@Wo  (f32 out to protect layernorm precision)
      gemm_k<4, 1><<<gemmN512, 256, 0, stream>>>(
          buf1, 512, wo, wo, wo, nullptr, nullptr, nullptr, yf, nullptr,
          CR, 512, 512);
      // nf = z + drnorm(y)
      norm_k<<<rowsDiv4, 256, 0, stream>>>(yf, buf0, gamma + l * 512,
                                           beta + l * 512, buf1);
      if (l == 0) {
        agg_k<<<rowsDiv4, 256, 0, stream>>>(buf1, buf2);
        gemm_k<2, 1><<<gemmN512, 256, 0, stream>>>(
            buf2, 512, WquT, WquT, WquT, buf0, buf0, buf0, nullptr, b_quat,
            CR, 512, 512);
      } else if (l == 1) {
        agg_k<<<rowsDiv4, 256, 0, stream>>>(buf1, buf2);
        gemm_k<2, 1><<<gemmN512, 256, 0, stream>>>(
            buf2, 512, WwvT, WwvT, WwvT, buf0, buf0, buf0, nullptr, b_wav,
            CR, 512, 512);
      }
    }
    // out = nf[:,8,:]@W_out + b_out  (f32)
    gemm_k<3, 1><<<CB >> 7, 256, 0, stream>>>(
        buf1 + 4096, 4608, WouT, WouT, WouT, nullptr, nullptr, nullptr,
        out + b0 * 128, b_out, CB, 128, 512);
  }
}

// Round 5
// 2114.313 us; speedup vs baseline: 1.6742x; 1.6742x over previous
//
#include <hip/hip_runtime.h>

typedef unsigned short u16;
typedef unsigned int u32;
typedef float f32x4 __attribute__((ext_vector_type(4)));
typedef __bf16 bf16x8 __attribute__((ext_vector_type(8)));
typedef u16 u16x8 __attribute__((ext_vector_type(8)));

__device__ __forceinline__ float bf2f(u16 v) {
  union { u32 u; float f; } c; c.u = ((u32)v) << 16; return c.f;
}
__device__ __forceinline__ u16 f2bf(float f) {
  union { float f; u32 u; } c; c.f = f;
  c.u += 0x7fffu + ((c.u >> 16) & 1u);
  return (u16)(c.u >> 16);
}
__device__ __forceinline__ float fast_tanh(float x) {
  float e = __expf(2.0f * x);
  return 1.0f - 2.0f / (e + 1.0f);   // NaN-safe at +/-inf of e
}
__device__ __forceinline__ void gload16(const void* g, void* l) {
  __builtin_amdgcn_global_load_lds((const __attribute__((address_space(1))) void*)g,
                                   (__attribute__((address_space(3))) void*)l, 16, 0, 0);
}
__device__ __forceinline__ bf16x8 ldfrag(const u16* p) {
  return __builtin_bit_cast(bf16x8, *(const u16x8*)p);
}

// ---------------------------------------------------------------- prep kernels
__global__ __launch_bounds__(256) void conv_bf(const float* __restrict__ s,
                                               u16* __restrict__ d, long n) {
  const long i = (long)blockIdx.x * 256 + threadIdx.x;
  if (i < n) d[i] = f2bf(s[i]);
}

// dst[l][n][k] = bf16(src[l][k][n])   (weights stored transposed, N x K row-major)
__global__ __launch_bounds__(256) void trans_conv(const float* __restrict__ src,
                                                  u16* __restrict__ dst,
                                                  int K, int N, int batch) {
  const long total = (long)batch * K * N;
  const long idx = (long)blockIdx.x * 256 + threadIdx.x;
  if (idx >= total) return;
  const long l = idx / ((long)K * N);
  const long rem = idx - l * (long)K * N;
  const int n = (int)(rem / K);
  const int k = (int)(rem - (long)n * K);
  dst[idx] = f2bf(src[l * (long)K * N + (long)k * N + n]);
}

// f32 transpose: dst[l][n][a] = src[l][a][n]  (for Wo)
__global__ __launch_bounds__(256) void transf32(const float* __restrict__ src,
                                                float* __restrict__ dst) {
  const long idx = (long)blockIdx.x * 256 + threadIdx.x;  // 3*512*512
  const long l = idx >> 18;
  const int rem = (int)(idx & 262143);
  const int n = rem >> 9, a = rem & 511;
  dst[idx] = src[l * 262144 + (long)a * 512 + n];
}

// Quaternion block-matrix, stored transposed: dst[n*512+k] = sign[kb][nb]*Wsel[kc][nc]
__global__ __launch_bounds__(256) void build_quat(const float* __restrict__ wr,
                                                  const float* __restrict__ wi,
                                                  const float* __restrict__ wj,
                                                  const float* __restrict__ wk,
                                                  u16* __restrict__ dst) {
  const int idx = blockIdx.x * 256 + threadIdx.x;   // n*512+k, 262144 total
  const int n = idx >> 9, k = idx & 511;
  const int kb = k >> 7, kc = k & 127, nb = n >> 7, nc = n & 127;
  const float* const srcs[4] = {wr, wi, wj, wk};
  const float sgn[4][4] = {{1,1,1,1},{-1,1,-1,1},{-1,1,1,-1},{-1,-1,1,1}};
  dst[idx] = f2bf(sgn[kb][nb] * srcs[kb ^ nb][kc * 128 + nc]);
}

// Wavelet fold, stored transposed: equal parity -> (lo+hi)/2, diff -> (lo-hi)/2
__global__ __launch_bounds__(256) void build_wav(const float* __restrict__ lo,
                                                 const float* __restrict__ hi,
                                                 u16* __restrict__ dst) {
  const int idx = blockIdx.x * 256 + threadIdx.x;   // n*512+k
  const int n = idx >> 9, k = idx & 511;
  const int d = k >> 1, c = n >> 1;
  const float a = lo[d * 256 + c], b = hi[d * 256 + c];
  dst[idx] = f2bf(((k ^ n) & 1) ? 0.5f * (a - b) : 0.5f * (a + b));
}

// Weight folds (f32 NT-GEMM, 64x64 tile): C[n][k] = sum_a L[n][a]*R[k][a] -> bf16.
// slot = bx>>6: slot&1==0 -> Wqk (L=Wk_l, R=Wq_l); ==1 -> Wvo (L=WoT_l, R=Wv_l).
__global__ __launch_bounds__(256) void fold_nt(const float* __restrict__ Wq,
                                               const float* __restrict__ Wk,
                                               const float* __restrict__ Wv,
                                               const float* __restrict__ WoT,
                                               u16* __restrict__ dst) {
  const int bx = blockIdx.x;
  const int slot = bx >> 6, l = slot >> 1, isvo = slot & 1;
  const float* L = isvo ? WoT + (size_t)l * 262144 : Wk + (size_t)l * 262144;
  const float* R = isvo ? Wv + (size_t)l * 262144 : Wq + (size_t)l * 262144;
  u16* D = dst + (size_t)l * 524288 + (size_t)isvo * 262144;
  const int t = bx & 63;
  const int n0 = (t >> 3) << 6, k0 = (t & 7) << 6;
  __shared__ float Lt[64][65];
  __shared__ float Rt[64][65];
  const int tid = threadIdx.x;
  const int tr = tid >> 4, tc = tid & 15;
  float acc[4][4] = {};
  for (int a0 = 0; a0 < 512; a0 += 64) {
    __syncthreads();
    #pragma unroll
    for (int r = 0; r < 4; ++r) {
      const int idx = r * 256 + tid;
      const int row = idx >> 4, c4 = (idx & 15) << 2;
      const f32x4 lv = *(const f32x4*)&L[(size_t)(n0 + row) * 512 + a0 + c4];
      const f32x4 rv = *(const f32x4*)&R[(size_t)(k0 + row) * 512 + a0 + c4];
      #pragma unroll
      for (int u = 0; u < 4; ++u) { Lt[row][c4 + u] = lv[u]; Rt[row][c4 + u] = rv[u]; }
    }
    __syncthreads();
    #pragma unroll 4
    for (int kk = 0; kk < 64; ++kk) {
      float lv[4], rv[4];
      #pragma unroll
      for (int i = 0; i < 4; ++i) lv[i] = Lt[tr * 4 + i][kk];
      #pragma unroll
      for (int j = 0; j < 4; ++j) rv[j] = Rt[tc * 4 + j][kk];
      #pragma unroll
      for (int i = 0; i < 4; ++i)
        #pragma unroll
        for (int j = 0; j < 4; ++j) acc[i][j] += lv[i] * rv[j];
    }
  }
  #pragma unroll
  for (int i = 0; i < 4; ++i)
    #pragma unroll
    for (int j = 0; j < 4; ++j)
      D[(size_t)(n0 + tr * 4 + i) * 512 + k0 + tc * 4 + j] = f2bf(acc[i][j]);
}

// ---------------------------------------------------------------- GEMM core
// 128x128 tile, BK=64, 4 waves each 64x64 (4x4 16x16x32 bf16 MFMA frags),
// global_load_lds(16) staging (m97 structure). B pre-transposed (N x K).
// bn-major block order: consecutive blocks share the A panel (L2 reuse).
// EPI: 0=none->bf16  1=bias+leaky->bf16  2=bias+tanh->bf16  3=bias->f32
template<int EPI>
__global__ __launch_bounds__(256, 2)
void gemm_k(const u16* __restrict__ A, int arow, const u16* __restrict__ BT,
            u16* __restrict__ C, float* __restrict__ Cf,
            const float* __restrict__ bias, int N, int K) {
  __shared__ u16 lsA[128 * 64];
  __shared__ u16 lsB[128 * 64];
  const int tid = threadIdx.x;
  const int nblk = N >> 7;
  const int bm = (int)blockIdx.x / nblk;        // bn-major: A panel shared
  const int bn = (int)blockIdx.x % nblk;
  const long m0 = (long)bm << 7;
  const int n0 = bn << 7;
  const int w = tid >> 6, lane = tid & 63;
  const int wrow = ((w >> 1) & 1) << 6;
  const int wcol = (w & 1) << 6;
  const int lr = lane & 15, lg = lane >> 4;

  f32x4 acc[4][4];
  #pragma unroll
  for (int i = 0; i < 4; ++i)
    #pragma unroll
    for (int j = 0; j < 4; ++j) acc[i][j] = (f32x4){0.f, 0.f, 0.f, 0.f};

  for (int kt = 0; kt < K; kt += 64) {
    __syncthreads();                          // protect LDS from prior reads
    #pragma unroll
    for (int r = 0; r < 4; ++r) {             // A tile: 1024 16B chunks
      const int chunk = r * 256 + tid;
      const int row = chunk >> 3, cc = (chunk & 7) << 3;
      gload16(A + (m0 + row) * (long)arow + kt + cc, &lsA[chunk * 8]);
    }
    #pragma unroll
    for (int r = 0; r < 4; ++r) {             // B^T tile
      const int chunk = r * 256 + tid;
      const int row = chunk >> 3, cc = (chunk & 7) << 3;
      gload16(BT + (size_t)(n0 + row) * K + kt + cc, &lsB[chunk * 8]);
    }
    __syncthreads();                          // vmcnt(0) drain before barrier
    #pragma unroll
    for (int kk = 0; kk < 64; kk += 32) {
      bf16x8 af[4], bfr[4];
      #pragma unroll
      for (int m = 0; m < 4; ++m)
        af[m] = ldfrag(&lsA[(wrow + m * 16 + lr) * 64 + kk + lg * 8]);
      #pragma unroll
      for (int n = 0; n < 4; ++n)
        bfr[n] = ldfrag(&lsB[(wcol + n * 16 + lr) * 64 + kk + lg * 8]);
      #pragma unroll
      for (int m = 0; m < 4; ++m)
        #pragma unroll
        for (int n = 0; n < 4; ++n)
          acc[m][n] = __builtin_amdgcn_mfma_f32_16x16x32_bf16(
              af[m], bfr[n], acc[m][n], 0, 0, 0);
    }
  }
  // epilogue: C/D layout col=lane&15, row=(lane>>4)*4+reg (m89-verified)
  #pragma unroll
  for (int m = 0; m < 4; ++m) {
    const long rbase = m0 + wrow + m * 16 + lg * 4;
    #pragma unroll
    for (int n = 0; n < 4; ++n) {
      const int col = n0 + wcol + n * 16 + lr;
      float bv = 0.f;
      if (EPI == 1 || EPI == 2 || EPI == 3) bv = bias[col];
      #pragma unroll
      for (int j = 0; j < 4; ++j) {
        float v = acc[m][n][j];
        const long row = rbase + j;
        if (EPI == 1) { v += bv; v = v > 0.f ? v : 0.01f * v; }
        if (EPI == 2) { v += bv; v = fast_tanh(v); }
        if (EPI == 3) { v += bv; }
        if (EPI == 3) Cf[row * N + col] = v;
        else          C[row * N + col] = f2bf(v);
      }
    }
  }
}

// ---------------------------------------------------------------- vortex agg
// m[b,node,:] = 0.5*(z[b,node,:] + z[b,(5*node+4)%9,:])   (node 8 -> itself)
__global__ __launch_bounds__(256) void agg_k(const u16* __restrict__ z,
                                             u16* __restrict__ mo) {
  const long idx = (long)blockIdx.x * 256 + threadIdx.x;  // u16x8 chunk id
  const int h0 = (int)(idx & 63) << 3;
  const long row = idx >> 6;
  const long b = row / 9;
  const int node = (int)(row - b * 9);
  const int srcn = (5 * node + 4) % 9;
  const u16x8 a = *(const u16x8*)&z[row * 512 + h0];
  const u16x8 c = *(const u16x8*)&z[(b * 9 + srcn) * 512 + h0];
  u16x8 o;
  #pragma unroll
  for (int u = 0; u < 8; ++u) o[u] = f2bf(0.5f * (bf2f(a[u]) + bf2f(c[u])));
  *(u16x8*)&mo[row * 512 + h0] = o;
}

// ---------------------------------------------------------------- fused attention
// sv = [s | vo] (CR x 1024): s = z@Wqk (cols 0..511), vo = z@(Wv@Wo) (cols 512..1023).
// scores_ij = s_i . z_j / sqrt(512); a = softmax; y_i = sum_j a_ij vo_j;
// nf_i = z_i + gamma*(y_i - mu)*rsqrt(var+eps) + beta.
// MODE 0: out = agg(nf) (9 rows per batch elem).  MODE 2: out = nf row 8 only.
// One wave per batch elem, 4 waves/block. No LDS staging (rows are L1-resident).
template<int MODE>
__global__ __launch_bounds__(256, 2)
void attn_fused(const u16* __restrict__ sv, const u16* __restrict__ z,
                const float* __restrict__ gamma, const float* __restrict__ beta,
                u16* __restrict__ outp) {
  __shared__ float laf[4][256];
  const int tid = threadIdx.x;
  const int wv = tid >> 6, lane = tid & 63;
  const long b = (long)blockIdx.x * 4 + wv;
  const long b9 = b * 9;
  const int lr = lane & 15, lg = lane >> 4;
  const int rr = lr > 8 ? 8 : lr;               // clamp pad rows (finite data)

  // scores via 16 MFMAs (layout validated end-to-end in R4 run)
  f32x4 sacc = {0.f, 0.f, 0.f, 0.f};
  const u16* srow = sv + (b9 + rr) * 1024;
  const u16* zrow = z + (b9 + rr) * 512;
  #pragma unroll
  for (int kc = 0; kc < 16; ++kc) {
    const bf16x8 qa = ldfrag(srow + kc * 32 + lg * 8);
    const bf16x8 kb = ldfrag(zrow + kc * 32 + lg * 8);
    sacc = __builtin_amdgcn_mfma_f32_16x16x32_bf16(qa, kb, sacc, 0, 0, 0);
  }
  const float scale = 0.0441941738241592f;      // 1/sqrt(512)
  #pragma unroll
  for (int r = 0; r < 4; ++r) {
    float s = sacc[r] * scale;
    if (lr > 8) s = -1e30f;                     // invalid key col
    float mx = s;
    #pragma unroll
    for (int m = 1; m < 16; m <<= 1) mx = fmaxf(mx, __shfl_xor(mx, m, 16));
    const float e = __expf(s - mx);
    float sum = e;
    #pragma unroll
    for (int m = 1; m < 16; m <<= 1) sum += __shfl_xor(sum, m, 16);
    laf[wv][(lg * 4 + r) * 16 + lr] = e / sum;  // a[i][j]
  }
  __syncthreads();

  constexpr int NR = (MODE == 0) ? 9 : 1;
  float o[NR][8];
  #pragma unroll
  for (int i = 0; i < NR; ++i)
    #pragma unroll
    for (int u = 0; u < 8; ++u) o[i][u] = 0.f;

  #pragma unroll
  for (int j = 0; j < 9; ++j) {                 // PV, j-outer (vo row read once)
    const u16x8 v8 = *(const u16x8*)&sv[(b9 + j) * 1024 + 512 + lane * 8];
    float vf[8];
    #pragma unroll
    for (int u = 0; u < 8; ++u) vf[u] = bf2f(v8[u]);
    #pragma unroll
    for (int i = 0; i < NR; ++i) {
      const float aij = laf[wv][((MODE == 0) ? i : 8) * 16 + j];
      #pragma unroll
      for (int u = 0; u < 8; ++u) o[i][u] += aij * vf[u];
    }
  }

  const f32x4 g0 = *(const f32x4*)&gamma[lane * 8];
  const f32x4 g1 = *(const f32x4*)&gamma[lane * 8 + 4];
  const f32x4 t0 = *(const f32x4*)&beta[lane * 8];
  const f32x4 t1 = *(const f32x4*)&beta[lane * 8 + 4];
  float gm[8] = {g0[0], g0[1], g0[2], g0[3], g1[0], g1[1], g1[2], g1[3]};
  float bt[8] = {t0[0], t0[1], t0[2], t0[3], t1[0], t1[1], t1[2], t1[3]};

  #pragma unroll
  for (int i = 0; i < NR; ++i) {                // layernorm + residual per row
    float s1 = 0.f, s2 = 0.f;
    #pragma unroll
    for (int u = 0; u < 8; ++u) { s1 += o[i][u]; s2 += o[i][u] * o[i][u]; }
    #pragma unroll
    for (int m = 1; m < 64; m <<= 1) {
      s1 += __shfl_xor(s1, m, 64); s2 += __shfl_xor(s2, m, 64);
    }
    const float mu = s1 * (1.f / 512.f);
    const float rv = rsqrtf(s2 * (1.f / 512.f) - mu * mu + 1e-5f);
    const int zi = (MODE == 0) ? i : 8;
    const u16x8 z8 = *(const u16x8*)&z[(b9 + zi) * 512 + lane * 8];
    #pragma unroll
    for (int u = 0; u < 8; ++u)
      o[i][u] = bf2f(z8[u]) + gm[u] * (o[i][u] - mu) * rv + bt[u];
  }

  if (MODE == 0) {                              // agg(nf) in registers
    #pragma unroll
    for (int i = 0; i < 9; ++i) {
      const int srcn = (5 * i + 4) % 9;
      u16x8 ov;
      #pragma unroll
      for (int u = 0; u < 8; ++u) ov[u] = f2bf(0.5f * (o[i][u] + o[srcn][u]));
      *(u16x8*)&outp[(b9 + i) * 512 + lane * 8] = ov;
    }
  } else {                                      // node-8 row only
    u16x8 ov;
    #pragma unroll
    for (int u = 0; u < 8; ++u) ov[u] = f2bf(o[0][u]);
    *(u16x8*)&outp[b * 512 + lane * 8] = ov;
  }
}

// ---------------------------------------------------------------- launcher
extern "C" void kernel_launch(void* const* d_in, const int* in_sizes, int n_in,
                              void* d_out, int out_size, void* d_ws, size_t ws_size,
                              hipStream_t stream) {
  (void)in_sizes; (void)n_in; (void)out_size;
  const float* x      = (const float*)d_in[0];
  const float* W_in   = (const float*)d_in[1];
  const float* b_in   = (const float*)d_in[2];
  const float* W_dr   = (const float*)d_in[3];
  const float* b_dr   = (const float*)d_in[4];
  const float* W_hyp  = (const float*)d_in[5];
  const float* b_hyp  = (const float*)d_in[6];
  const float* Wq_r   = (const float*)d_in[7];
  const float* Wq_i   = (const float*)d_in[8];
  const float* Wq_j   = (const float*)d_in[9];
  const float* Wq_k   = (const float*)d_in[10];
  const float* b_quat = (const float*)d_in[11];
  const float* W_low  = (const float*)d_in[12];
  const float* W_high = (const float*)d_in[13];
  const float* b_wav  = (const float*)d_in[14];
  const float* aWq    = (const float*)d_in[15];
  const float* aWk    = (const float*)d_in[16];
  const float* aWv    = (const float*)d_in[17];
  const float* aWo    = (const float*)d_in[18];
  const float* gamma  = (const float*)d_in[19];
  const float* beta   = (const float*)d_in[20];
  const float* W_out  = (const float*)d_in[21];
  const float* b_out  = (const float*)d_in[22];
  float* out = (float*)d_out;

  // ---- workspace: [weights ~13.2 MB][per-chunk activations] ----
  char* ws = (char*)d_ws;
  char* wp = ws;
  u16* WinT   = (u16*)wp;  wp += (size_t)4608 * 512 * 2;  // 4.72 MB
  u16* WdrT   = (u16*)wp;  wp += 524288;
  u16* WhyT   = (u16*)wp;  wp += 524288;
  u16* WquT   = (u16*)wp;  wp += 524288;
  u16* WwvT   = (u16*)wp;  wp += 524288;
  u16* BTqkvo = (u16*)wp;  wp += 3 * 1024 * 512 * 2;      // 3.15 MB
  u16* WouT   = (u16*)wp;  wp += 131072;
  float* WoTf = (float*)wp; wp += 3 * 512 * 512 * 4;      // 3.15 MB
  const size_t woff = (size_t)(wp - ws);

  // chunk count: smallest NC (>=2, pow2) fitting ws_size.
  // per-chunk = CB*1024 (xbf/nf8) + 2*CB*9216 (buf0,buf1) + CB*18432 (sv) = CB*37888
  int nc = 2;
  while (nc < 64 && woff + (size_t)(16384 / nc) * 37888ULL > ws_size) nc *= 2;
  const int CB = 16384 / nc;
  const int CR = CB * 9;

  char* cbase = ws + woff;
  u16* xbf  = (u16*)cbase;                       // CB x 512 (also nf8 out)
  u16* buf0 = (u16*)(cbase + (size_t)CB * 1024); // CR x 512
  u16* buf1 = buf0 + (size_t)CR * 512;           // CR x 512
  u16* sv   = buf1 + (size_t)CR * 512;           // CR x 1024 (also agg scratch)

  // ---- weight prep ----
  trans_conv<<<9216, 256, 0, stream>>>(W_in, WinT, 512, 4608, 1);
  trans_conv<<<1024, 256, 0, stream>>>(W_dr, WdrT, 512, 512, 1);
  trans_conv<<<1024, 256, 0, stream>>>(W_hyp, WhyT, 512, 512, 1);
  trans_conv<<<256, 256, 0, stream>>>(W_out, WouT, 512, 128, 1);
  build_quat<<<1024, 256, 0, stream>>>(Wq_r, Wq_i, Wq_j, Wq_k, WquT);
  build_wav<<<1024, 256, 0, stream>>>(W_low, W_high, WwvT);
  transf32<<<3072, 256, 0, stream>>>(aWo, WoTf);
  fold_nt<<<384, 256, 0, stream>>>(aWq, aWk, aWv, WoTf, BTqkvo);

  const int g512 = (CR >> 7) * 4;               // (CR,512) gemm grid
  const int g1024 = (CR >> 7) * 8;              // (CR,1024) gemm grid
  const int rowsDiv4 = CR >> 2;                 // agg grid

  for (int c = 0; c < nc; ++c) {
    const size_t b0 = (size_t)c * CB;
    conv_bf<<<CB * 2, 256, 0, stream>>>(x + b0 * 512, xbf, (long)CB * 512);
    // p = leaky(x@W_in+b_in)   (M=CB, N=4608)
    gemm_k<1><<<(CB >> 7) * 36, 256, 0, stream>>>(
        xbf, 512, WinT, buf0, nullptr, b_in, 4608, 512);
    // nf = tanh(p@W_dr+b_dr)
    gemm_k<2><<<g512, 256, 0, stream>>>(
        buf0, 512, WdrT, buf1, nullptr, b_dr, 512, 512);
    agg_k<<<rowsDiv4, 256, 0, stream>>>(buf1, sv);   // sv as scratch
    // z = tanh(agg@W_hyp+b_hyp)
    gemm_k<2><<<g512, 256, 0, stream>>>(
        sv, 512, WhyT, buf0, nullptr, b_hyp, 512, 512);

    for (int l = 0; l < 3; ++l) {
      // [s|vo] = z @ [Wqk | Wvo]   (N=1024)
      gemm_k<0><<<g1024, 256, 0, stream>>>(
          buf0, 512, BTqkvo + (size_t)l * 524288, sv, nullptr, nullptr,
          1024, 512);
      if (l < 2) {
        // m = agg(z + drnorm(attn))
        attn_fused<0><<<CB / 4, 256, 0, stream>>>(
            sv, buf0, gamma + l * 512, beta + l * 512, buf1);
        // z' = tanh(m@W + b)
        gemm_k<2><<<g512, 256, 0, stream>>>(
            buf1, 512, (l == 0) ? WquT : WwvT, buf0, nullptr,
            (l == 0) ? b_quat : b_wav, 512, 512);
      } else {
        // nf node-8 rows only
        attn_fused<2><<<CB / 4, 256, 0, stream>>>(
            sv, buf0, gamma + 2 * 512, beta + 2 * 512, xbf);
      }
    }
    // out = nf8 @ W_out + b_out  (f32)
    gemm_k<3><<<CB >> 7, 256, 0, stream>>>(
        xbf, 512, WouT, nullptr, out + b0 * 128, b_out, 128, 512);
  }
}

// Round 6
// 1941.792 us; speedup vs baseline: 1.8230x; 1.0888x over previous
//
#include <hip/hip_runtime.h>

typedef unsigned short u16;
typedef unsigned int u32;
typedef float f32x4 __attribute__((ext_vector_type(4)));
typedef __bf16 bf16x8 __attribute__((ext_vector_type(8)));
typedef u16 u16x8 __attribute__((ext_vector_type(8)));

__device__ __forceinline__ float bf2f(u16 v) {
  union { u32 u; float f; } c; c.u = ((u32)v) << 16; return c.f;
}
__device__ __forceinline__ u16 f2bf(float f) {
  union { float f; u32 u; } c; c.f = f;
  c.u += 0x7fffu + ((c.u >> 16) & 1u);
  return (u16)(c.u >> 16);
}
__device__ __forceinline__ float fast_tanh(float x) {
  float e = __expf(2.0f * x);
  return 1.0f - 2.0f / (e + 1.0f);   // NaN-safe at +/-inf of e
}
__device__ __forceinline__ void gload16(const void* g, void* l) {
  __builtin_amdgcn_global_load_lds((const __attribute__((address_space(1))) void*)g,
                                   (__attribute__((address_space(3))) void*)l, 16, 0, 0);
}
__device__ __forceinline__ bf16x8 ldfrag(const u16* p) {
  return __builtin_bit_cast(bf16x8, *(const u16x8*)p);
}
// Bijective XCD swizzle (m204): XCD x owns a contiguous range of logical ids.
__device__ __forceinline__ int xcd_swizzle() {
  const int nwg = (int)gridDim.x, orig = (int)blockIdx.x;
  const int q = nwg >> 3, r = nwg & 7;
  const int xcd = orig & 7, idx = orig >> 3;
  return (xcd < r ? xcd * (q + 1) : r * (q + 1) + (xcd - r) * q) + idx;
}

// ---------------------------------------------------------------- prep kernels
__global__ __launch_bounds__(256) void conv_bf(const float* __restrict__ s,
                                               u16* __restrict__ d, long n) {
  const long i = (long)blockIdx.x * 256 + threadIdx.x;
  if (i < n) d[i] = f2bf(s[i]);
}

// dst[l][n][k] = bf16(src[l][k][n])   (weights stored transposed, N x K row-major)
__global__ __launch_bounds__(256) void trans_conv(const float* __restrict__ src,
                                                  u16* __restrict__ dst,
                                                  int K, int N, int batch) {
  const long total = (long)batch * K * N;
  const long idx = (long)blockIdx.x * 256 + threadIdx.x;
  if (idx >= total) return;
  const long l = idx / ((long)K * N);
  const long rem = idx - l * (long)K * N;
  const int n = (int)(rem / K);
  const int k = (int)(rem - (long)n * K);
  dst[idx] = f2bf(src[l * (long)K * N + (long)k * N + n]);
}

// f32 transpose: dst[l][n][a] = src[l][a][n]  (for Wo)
__global__ __launch_bounds__(256) void transf32(const float* __restrict__ src,
                                                float* __restrict__ dst) {
  const long idx = (long)blockIdx.x * 256 + threadIdx.x;  // 3*512*512
  const long l = idx >> 18;
  const int rem = (int)(idx & 262143);
  const int n = rem >> 9, a = rem & 511;
  dst[idx] = src[l * 262144 + (long)a * 512 + n];
}

// Quaternion block-matrix, stored transposed: dst[n*512+k] = sign[kb][nb]*Wsel[kc][nc]
__global__ __launch_bounds__(256) void build_quat(const float* __restrict__ wr,
                                                  const float* __restrict__ wi,
                                                  const float* __restrict__ wj,
                                                  const float* __restrict__ wk,
                                                  u16* __restrict__ dst) {
  const int idx = blockIdx.x * 256 + threadIdx.x;   // n*512+k, 262144 total
  const int n = idx >> 9, k = idx & 511;
  const int kb = k >> 7, kc = k & 127, nb = n >> 7, nc = n & 127;
  const float* const srcs[4] = {wr, wi, wj, wk};
  const float sgn[4][4] = {{1,1,1,1},{-1,1,-1,1},{-1,1,1,-1},{-1,-1,1,1}};
  dst[idx] = f2bf(sgn[kb][nb] * srcs[kb ^ nb][kc * 128 + nc]);
}

// Wavelet fold, stored transposed: equal parity -> (lo+hi)/2, diff -> (lo-hi)/2
__global__ __launch_bounds__(256) void build_wav(const float* __restrict__ lo,
                                                 const float* __restrict__ hi,
                                                 u16* __restrict__ dst) {
  const int idx = blockIdx.x * 256 + threadIdx.x;   // n*512+k
  const int n = idx >> 9, k = idx & 511;
  const int d = k >> 1, c = n >> 1;
  const float a = lo[d * 256 + c], b = hi[d * 256 + c];
  dst[idx] = f2bf(((k ^ n) & 1) ? 0.5f * (a - b) : 0.5f * (a + b));
}

// Weight folds (f32 NT-GEMM, 64x64 tile): C[n][k] = sum_a L[n][a]*R[k][a] -> bf16.
// slot = bx>>6: slot&1==0 -> Wqk (L=Wk_l, R=Wq_l); ==1 -> Wvo (L=WoT_l, R=Wv_l).
__global__ __launch_bounds__(256) void fold_nt(const float* __restrict__ Wq,
                                               const float* __restrict__ Wk,
                                               const float* __restrict__ Wv,
                                               const float* __restrict__ WoT,
                                               u16* __restrict__ dst) {
  const int bx = blockIdx.x;
  const int slot = bx >> 6, l = slot >> 1, isvo = slot & 1;
  const float* L = isvo ? WoT + (size_t)l * 262144 : Wk + (size_t)l * 262144;
  const float* R = isvo ? Wv + (size_t)l * 262144 : Wq + (size_t)l * 262144;
  u16* D = dst + (size_t)l * 524288 + (size_t)isvo * 262144;
  const int t = bx & 63;
  const int n0 = (t >> 3) << 6, k0 = (t & 7) << 6;
  __shared__ float Lt[64][65];
  __shared__ float Rt[64][65];
  const int tid = threadIdx.x;
  const int tr = tid >> 4, tc = tid & 15;
  float acc[4][4] = {};
  for (int a0 = 0; a0 < 512; a0 += 64) {
    __syncthreads();
    #pragma unroll
    for (int r = 0; r < 4; ++r) {
      const int idx = r * 256 + tid;
      const int row = idx >> 4, c4 = (idx & 15) << 2;
      const f32x4 lv = *(const f32x4*)&L[(size_t)(n0 + row) * 512 + a0 + c4];
      const f32x4 rv = *(const f32x4*)&R[(size_t)(k0 + row) * 512 + a0 + c4];
      #pragma unroll
      for (int u = 0; u < 4; ++u) { Lt[row][c4 + u] = lv[u]; Rt[row][c4 + u] = rv[u]; }
    }
    __syncthreads();
    #pragma unroll 4
    for (int kk = 0; kk < 64; ++kk) {
      float lv[4], rv[4];
      #pragma unroll
      for (int i = 0; i < 4; ++i) lv[i] = Lt[tr * 4 + i][kk];
      #pragma unroll
      for (int j = 0; j < 4; ++j) rv[j] = Rt[tc * 4 + j][kk];
      #pragma unroll
      for (int i = 0; i < 4; ++i)
        #pragma unroll
        for (int j = 0; j < 4; ++j) acc[i][j] += lv[i] * rv[j];
    }
  }
  #pragma unroll
  for (int i = 0; i < 4; ++i)
    #pragma unroll
    for (int j = 0; j < 4; ++j)
      D[(size_t)(n0 + tr * 4 + i) * 512 + k0 + tc * 4 + j] = f2bf(acc[i][j]);
}

// ---------------------------------------------------------------- GEMM core
// 128x128 tile, BK=64, 4 waves each 64x64 (4x4 16x16x32 bf16 MFMA frags),
// global_load_lds(16) staging (m97 structure). B pre-transposed (N x K).
// bn-major logical order + bijective XCD swizzle: A-panel-sharing blocks
// land on ONE XCD's L2 (R5 counter: FETCH was 2x ideal from cross-XCD split).
// EPI: 0=none->bf16  1=bias+leaky->bf16  2=bias+tanh->bf16  3=bias->f32
template<int EPI>
__global__ __launch_bounds__(256, 3)
void gemm_k(const u16* __restrict__ A, int arow, const u16* __restrict__ BT,
            u16* __restrict__ C, float* __restrict__ Cf,
            const float* __restrict__ bias, int N, int K) {
  __shared__ u16 lsA[128 * 64];
  __shared__ u16 lsB[128 * 64];
  const int tid = threadIdx.x;
  const int nblk = N >> 7;
  const int bx = xcd_swizzle();
  const int bm = bx / nblk;                     // bn-major: A panel shared
  const int bn = bx % nblk;
  const long m0 = (long)bm << 7;
  const int n0 = bn << 7;
  const int w = tid >> 6, lane = tid & 63;
  const int wrow = ((w >> 1) & 1) << 6;
  const int wcol = (w & 1) << 6;
  const int lr = lane & 15, lg = lane >> 4;

  f32x4 acc[4][4];
  #pragma unroll
  for (int i = 0; i < 4; ++i)
    #pragma unroll
    for (int j = 0; j < 4; ++j) acc[i][j] = (f32x4){0.f, 0.f, 0.f, 0.f};

  for (int kt = 0; kt < K; kt += 64) {
    __syncthreads();                          // protect LDS from prior reads
    #pragma unroll
    for (int r = 0; r < 4; ++r) {             // A tile: 1024 16B chunks
      const int chunk = r * 256 + tid;
      const int row = chunk >> 3, cc = (chunk & 7) << 3;
      gload16(A + (m0 + row) * (long)arow + kt + cc, &lsA[chunk * 8]);
    }
    #pragma unroll
    for (int r = 0; r < 4; ++r) {             // B^T tile
      const int chunk = r * 256 + tid;
      const int row = chunk >> 3, cc = (chunk & 7) << 3;
      gload16(BT + (size_t)(n0 + row) * K + kt + cc, &lsB[chunk * 8]);
    }
    __syncthreads();                          // vmcnt(0) drain before barrier
    #pragma unroll
    for (int kk = 0; kk < 64; kk += 32) {
      bf16x8 af[4], bfr[4];
      #pragma unroll
      for (int m = 0; m < 4; ++m)
        af[m] = ldfrag(&lsA[(wrow + m * 16 + lr) * 64 + kk + lg * 8]);
      #pragma unroll
      for (int n = 0; n < 4; ++n)
        bfr[n] = ldfrag(&lsB[(wcol + n * 16 + lr) * 64 + kk + lg * 8]);
      #pragma unroll
      for (int m = 0; m < 4; ++m)
        #pragma unroll
        for (int n = 0; n < 4; ++n)
          acc[m][n] = __builtin_amdgcn_mfma_f32_16x16x32_bf16(
              af[m], bfr[n], acc[m][n], 0, 0, 0);
    }
  }
  // epilogue: C/D layout col=lane&15, row=(lane>>4)*4+reg (m89-verified)
  #pragma unroll
  for (int m = 0; m < 4; ++m) {
    const long rbase = m0 + wrow + m * 16 + lg * 4;
    #pragma unroll
    for (int n = 0; n < 4; ++n) {
      const int col = n0 + wcol + n * 16 + lr;
      float bv = 0.f;
      if (EPI == 1 || EPI == 2 || EPI == 3) bv = bias[col];
      #pragma unroll
      for (int j = 0; j < 4; ++j) {
        float v = acc[m][n][j];
        const long row = rbase + j;
        if (EPI == 1) { v += bv; v = v > 0.f ? v : 0.01f * v; }
        if (EPI == 2) { v += bv; v = fast_tanh(v); }
        if (EPI == 3) { v += bv; }
        if (EPI == 3) Cf[row * N + col] = v;
        else          C[row * N + col] = f2bf(v);
      }
    }
  }
}

// ---------------------------------------------------------------- vortex agg
// m[b,node,:] = 0.5*(z[b,node,:] + z[b,(5*node+4)%9,:])   (node 8 -> itself)
__global__ __launch_bounds__(256) void agg_k(const u16* __restrict__ z,
                                             u16* __restrict__ mo) {
  const long idx = (long)blockIdx.x * 256 + threadIdx.x;  // u16x8 chunk id
  const int h0 = (int)(idx & 63) << 3;
  const long row = idx >> 6;
  const long b = row / 9;
  const int node = (int)(row - b * 9);
  const int srcn = (5 * node + 4) % 9;
  const u16x8 a = *(const u16x8*)&z[row * 512 + h0];
  const u16x8 c = *(const u16x8*)&z[(b * 9 + srcn) * 512 + h0];
  u16x8 o;
  #pragma unroll
  for (int u = 0; u < 8; ++u) o[u] = f2bf(0.5f * (bf2f(a[u]) + bf2f(c[u])));
  *(u16x8*)&mo[row * 512 + h0] = o;
}

// ---------------------------------------------------------------- fused attention
// sv = [s | vo] (CR x 1024): s = z@Wqk (cols 0..511), vo = z@(Wv@Wo) (cols 512..1023).
// scores_ij = s_i . z_j / sqrt(512); a = softmax; y_i = sum_j a_ij vo_j;
// nf_i = z_i + gamma*(y_i - mu)*rsqrt(var+eps) + beta.
// MODE 0: out = agg(nf) (9 rows per batch elem).  MODE 2: out = nf row 8 only.
// One wave per batch elem, 4 waves/block. No LDS staging (rows are L1-resident).
template<int MODE>
__global__ __launch_bounds__(256, 2)
void attn_fused(const u16* __restrict__ sv, const u16* __restrict__ z,
                const float* __restrict__ gamma, const float* __restrict__ beta,
                u16* __restrict__ outp) {
  __shared__ float laf[4][256];
  const int tid = threadIdx.x;
  const int wv = tid >> 6, lane = tid & 63;
  const long b = (long)blockIdx.x * 4 + wv;
  const long b9 = b * 9;
  const int lr = lane & 15, lg = lane >> 4;
  const int rr = lr > 8 ? 8 : lr;               // clamp pad rows (finite data)

  // scores via 16 MFMAs
  f32x4 sacc = {0.f, 0.f, 0.f, 0.f};
  const u16* srow = sv + (b9 + rr) * 1024;
  const u16* zrow = z + (b9 + rr) * 512;
  #pragma unroll
  for (int kc = 0; kc < 16; ++kc) {
    const bf16x8 qa = ldfrag(srow + kc * 32 + lg * 8);
    const bf16x8 kb = ldfrag(zrow + kc * 32 + lg * 8);
    sacc = __builtin_amdgcn_mfma_f32_16x16x32_bf16(qa, kb, sacc, 0, 0, 0);
  }
  const float scale = 0.0441941738241592f;      // 1/sqrt(512)
  #pragma unroll
  for (int r = 0; r < 4; ++r) {
    float s = sacc[r] * scale;
    if (lr > 8) s = -1e30f;                     // invalid key col
    float mx = s;
    #pragma unroll
    for (int m = 1; m < 16; m <<= 1) mx = fmaxf(mx, __shfl_xor(mx, m, 16));
    const float e = __expf(s - mx);
    float sum = e;
    #pragma unroll
    for (int m = 1; m < 16; m <<= 1) sum += __shfl_xor(sum, m, 16);
    laf[wv][(lg * 4 + r) * 16 + lr] = e / sum;  // a[i][j]
  }
  __syncthreads();

  constexpr int NR = (MODE == 0) ? 9 : 1;
  float o[NR][8];
  #pragma unroll
  for (int i = 0; i < NR; ++i)
    #pragma unroll
    for (int u = 0; u < 8; ++u) o[i][u] = 0.f;

  #pragma unroll
  for (int j = 0; j < 9; ++j) {                 // PV, j-outer (vo row read once)
    const u16x8 v8 = *(const u16x8*)&sv[(b9 + j) * 1024 + 512 + lane * 8];
    float vf[8];
    #pragma unroll
    for (int u = 0; u < 8; ++u) vf[u] = bf2f(v8[u]);
    #pragma unroll
    for (int i = 0; i < NR; ++i) {
      const float aij = laf[wv][((MODE == 0) ? i : 8) * 16 + j];
      #pragma unroll
      for (int u = 0; u < 8; ++u) o[i][u] += aij * vf[u];
    }
  }

  const f32x4 g0 = *(const f32x4*)&gamma[lane * 8];
  const f32x4 g1 = *(const f32x4*)&gamma[lane * 8 + 4];
  const f32x4 t0 = *(const f32x4*)&beta[lane * 8];
  const f32x4 t1 = *(const f32x4*)&beta[lane * 8 + 4];
  float gm[8] = {g0[0], g0[1], g0[2], g0[3], g1[0], g1[1], g1[2], g1[3]};
  float bt[8] = {t0[0], t0[1], t0[2], t0[3], t1[0], t1[1], t1[2], t1[3]};

  #pragma unroll
  for (int i = 0; i < NR; ++i) {                // layernorm + residual per row
    float s1 = 0.f, s2 = 0.f;
    #pragma unroll
    for (int u = 0; u < 8; ++u) { s1 += o[i][u]; s2 += o[i][u] * o[i][u]; }
    #pragma unroll
    for (int m = 1; m < 64; m <<= 1) {
      s1 += __shfl_xor(s1, m, 64); s2 += __shfl_xor(s2, m, 64);
    }
    const float mu = s1 * (1.f / 512.f);
    const float rv = rsqrtf(s2 * (1.f / 512.f) - mu * mu + 1e-5f);
    const int zi = (MODE == 0) ? i : 8;
    const u16x8 z8 = *(const u16x8*)&z[(b9 + zi) * 512 + lane * 8];
    #pragma unroll
    for (int u = 0; u < 8; ++u)
      o[i][u] = bf2f(z8[u]) + gm[u] * (o[i][u] - mu) * rv + bt[u];
  }

  if (MODE == 0) {                              // agg(nf) in registers
    #pragma unroll
    for (int i = 0; i < 9; ++i) {
      const int srcn = (5 * i + 4) % 9;
      u16x8 ov;
      #pragma unroll
      for (int u = 0; u < 8; ++u) ov[u] = f2bf(0.5f * (o[i][u] + o[srcn][u]));
      *(u16x8*)&outp[(b9 + i) * 512 + lane * 8] = ov;
    }
  } else {                                      // node-8 row only
    u16x8 ov;
    #pragma unroll
    for (int u = 0; u < 8; ++u) ov[u] = f2bf(o[0][u]);
    *(u16x8*)&outp[b * 512 + lane * 8] = ov;
  }
}

// ---------------------------------------------------------------- launcher
extern "C" void kernel_launch(void* const* d_in, const int* in_sizes, int n_in,
                              void* d_out, int out_size, void* d_ws, size_t ws_size,
                              hipStream_t stream) {
  (void)in_sizes; (void)n_in; (void)out_size;
  const float* x      = (const float*)d_in[0];
  const float* W_in   = (const float*)d_in[1];
  const float* b_in   = (const float*)d_in[2];
  const float* W_dr   = (const float*)d_in[3];
  const float* b_dr   = (const float*)d_in[4];
  const float* W_hyp  = (const float*)d_in[5];
  const float* b_hyp  = (const float*)d_in[6];
  const float* Wq_r   = (const float*)d_in[7];
  const float* Wq_i   = (const float*)d_in[8];
  const float* Wq_j   = (const float*)d_in[9];
  const float* Wq_k   = (const float*)d_in[10];
  const float* b_quat = (const float*)d_in[11];
  const float* W_low  = (const float*)d_in[12];
  const float* W_high = (const float*)d_in[13];
  const float* b_wav  = (const float*)d_in[14];
  const float* aWq    = (const float*)d_in[15];
  const float* aWk    = (const float*)d_in[16];
  const float* aWv    = (const float*)d_in[17];
  const float* aWo    = (const float*)d_in[18];
  const float* gamma  = (const float*)d_in[19];
  const float* beta   = (const float*)d_in[20];
  const float* W_out  = (const float*)d_in[21];
  const float* b_out  = (const float*)d_in[22];
  float* out = (float*)d_out;

  // ---- workspace: [weights ~13.2 MB][per-chunk activations] ----
  char* ws = (char*)d_ws;
  char* wp = ws;
  u16* WinT   = (u16*)wp;  wp += (size_t)4608 * 512 * 2;  // 4.72 MB
  u16* WdrT   = (u16*)wp;  wp += 524288;
  u16* WhyT   = (u16*)wp;  wp += 524288;
  u16* WquT   = (u16*)wp;  wp += 524288;
  u16* WwvT   = (u16*)wp;  wp += 524288;
  u16* BTqkvo = (u16*)wp;  wp += 3 * 1024 * 512 * 2;      // 3.15 MB
  u16* WouT   = (u16*)wp;  wp += 131072;
  float* WoTf = (float*)wp; wp += 3 * 512 * 512 * 4;      // 3.15 MB
  const size_t woff = (size_t)(wp - ws);

  // chunk count: smallest NC (>=2, pow2) fitting ws_size.
  // per-chunk = CB*1024 (xbf/nf8) + 2*CB*9216 (buf0,buf1) + CB*18432 (sv) = CB*37888
  int nc = 2;
  while (nc < 64 && woff + (size_t)(16384 / nc) * 37888ULL > ws_size) nc *= 2;
  const int CB = 16384 / nc;
  const int CR = CB * 9;

  char* cbase = ws + woff;
  u16* xbf  = (u16*)cbase;                       // CB x 512 (also nf8 out)
  u16* buf0 = (u16*)(cbase + (size_t)CB * 1024); // CR x 512
  u16* buf1 = buf0 + (size_t)CR * 512;           // CR x 512
  u16* sv   = buf1 + (size_t)CR * 512;           // CR x 1024 (also agg scratch)

  // ---- weight prep ----
  trans_conv<<<9216, 256, 0, stream>>>(W_in, WinT, 512, 4608, 1);
  trans_conv<<<1024, 256, 0, stream>>>(W_dr, WdrT, 512, 512, 1);
  trans_conv<<<1024, 256, 0, stream>>>(W_hyp, WhyT, 512, 512, 1);
  trans_conv<<<256, 256, 0, stream>>>(W_out, WouT, 512, 128, 1);
  build_quat<<<1024, 256, 0, stream>>>(Wq_r, Wq_i, Wq_j, Wq_k, WquT);
  build_wav<<<1024, 256, 0, stream>>>(W_low, W_high, WwvT);
  transf32<<<3072, 256, 0, stream>>>(aWo, WoTf);
  fold_nt<<<384, 256, 0, stream>>>(aWq, aWk, aWv, WoTf, BTqkvo);

  const int g512 = (CR >> 7) * 4;               // (CR,512) gemm grid
  const int g1024 = (CR >> 7) * 8;              // (CR,1024) gemm grid
  const int rowsDiv4 = CR >> 2;                 // agg grid

  for (int c = 0; c < nc; ++c) {
    const size_t b0 = (size_t)c * CB;
    conv_bf<<<CB * 2, 256, 0, stream>>>(x + b0 * 512, xbf, (long)CB * 512);
    // p = leaky(x@W_in+b_in)   (M=CB, N=4608)
    gemm_k<1><<<(CB >> 7) * 36, 256, 0, stream>>>(
        xbf, 512, WinT, buf0, nullptr, b_in, 4608, 512);
    // nf = tanh(p@W_dr+b_dr)
    gemm_k<2><<<g512, 256, 0, stream>>>(
        buf0, 512, WdrT, buf1, nullptr, b_dr, 512, 512);
    agg_k<<<rowsDiv4, 256, 0, stream>>>(buf1, sv);   // sv as scratch
    // z = tanh(agg@W_hyp+b_hyp)
    gemm_k<2><<<g512, 256, 0, stream>>>(
        sv, 512, WhyT, buf0, nullptr, b_hyp, 512, 512);

    for (int l = 0; l < 3; ++l) {
      // [s|vo] = z @ [Wqk | Wvo]   (N=1024)
      gemm_k<0><<<g1024, 256, 0, stream>>>(
          buf0, 512, BTqkvo + (size_t)l * 524288, sv, nullptr, nullptr,
          1024, 512);
      if (l < 2) {
        // m = agg(z + drnorm(attn))
        attn_fused<0><<<CB / 4, 256, 0, stream>>>(
            sv, buf0, gamma + l * 512, beta + l * 512, buf1);
        // z' = tanh(m@W + b)
        gemm_k<2><<<g512, 256, 0, stream>>>(
            buf1, 512, (l == 0) ? WquT : WwvT, buf0, nullptr,
            (l == 0) ? b_quat : b_wav, 512, 512);
      } else {
        // nf node-8 rows only
        attn_fused<2><<<CB / 4, 256, 0, stream>>>(
            sv, buf0, gamma + 2 * 512, beta + 2 * 512, xbf);
      }
    }
    // out = nf8 @ W_out + b_out  (f32)
    gemm_k<3><<<CB >> 7, 256, 0, stream>>>(
        xbf, 512, WouT, nullptr, out + b0 * 128, b_out, 128, 512);
  }
}